// Round 4
// baseline (23788.321 us; speedup 1.0000x reference)
//
#include <hip/hip_runtime.h>
#include <cstdint>
#include <cstddef>

typedef __attribute__((ext_vector_type(8))) short bf16x8;
typedef __attribute__((ext_vector_type(4))) float f32x4;
typedef uint16_t u16;
typedef uint64_t u64;

#define NS 4096

// ---------------- fixed workspace layout (bytes) ----------------
#define OFF_FLAGS  ((size_t)0)                        //   4 KB
#define OFF_HX     ((size_t)4096)                     //  64 KB
#define OFF_STATE  ((size_t)(4096 + 65536))           // 128 KB: c then h, f32 [64][256] each
#define OFF_WHT    ((size_t)204800)                   // 512 KB
#define OFF_WXTH   (OFF_WHT   + (size_t)524288)
#define OFF_WXTL   (OFF_WXTH  + (size_t)262144)
#define OFF_WEF1H  (OFF_WXTL  + (size_t)262144)
#define OFF_WEF1L  (OFF_WEF1H + (size_t)32768)
#define OFF_WEF3H  (OFF_WEF1L + (size_t)32768)
#define OFF_WEF3L  (OFF_WEF3H + (size_t)65536)
#define OFF_CH     ((size_t)2*1024*1024)              // chunk region
// per-step: s hi/lo + x hi/lo + e1 hi/lo (6x16KB) + xw f32 (256KB) + j f32 (64KB)
#define CH_BYTES_PER_SC ((size_t)425984)

// ---------------- helpers ----------------
static __device__ __forceinline__ float bf2f(u16 u){
  union { uint32_t i; float f; } v; v.i = ((uint32_t)u) << 16; return v.f;
}
static __device__ __forceinline__ u16 f2bf(float f){
  union { float f; uint32_t u; } v; v.f = f;
  uint32_t r = v.u + 0x7fffu + ((v.u >> 16) & 1u);
  return (u16)(r >> 16);
}
static __device__ __forceinline__ float sigmoid_f(float x){
  return 1.f / (1.f + __expf(-x));
}
static __device__ __forceinline__ float tanh_f(float x){
  x = fminf(15.f, fmaxf(-15.f, x));
  float e = __expf(2.f * x);
  return 1.f - 2.f / (e + 1.f);
}
static __device__ __forceinline__ void glds16(const void* gp, void* lp){
  typedef __attribute__((address_space(1))) const unsigned int GU;
  typedef __attribute__((address_space(3))) unsigned int LU;
  __builtin_amdgcn_global_load_lds((GU*)gp, (LU*)lp, 16, 0, 0);
}
static __device__ __forceinline__ u64 agld64(const u64* p){
  return __hip_atomic_load(p, __ATOMIC_RELAXED, __HIP_MEMORY_SCOPE_AGENT);
}
static __device__ __forceinline__ float agldf(const float* p){
  return __hip_atomic_load(p, __ATOMIC_RELAXED, __HIP_MEMORY_SCOPE_AGENT);
}
static __device__ __forceinline__ void agst16(u16* p, u16 v){
  __hip_atomic_store(p, v, __ATOMIC_RELAXED, __HIP_MEMORY_SCOPE_AGENT);
}

// ---------------- K0: weight transpose/convert (hi/lo split for GEMM weights) ----------------
__global__ void k_prep(const float* __restrict__ Wh, const float* __restrict__ Wx,
                       const float* __restrict__ Wef1, const float* __restrict__ Wef3,
                       u16* __restrict__ WhT,
                       u16* __restrict__ WxTh, u16* __restrict__ WxTl,
                       u16* __restrict__ Wef1h, u16* __restrict__ Wef1l,
                       u16* __restrict__ Wef3h, u16* __restrict__ Wef3l){
  int idx = blockIdx.x*256 + threadIdx.x;
  if (idx < 262144){ int n = idx>>8, k = idx&255; WhT[idx] = f2bf(Wh[k*1024+n]); return; }
  idx -= 262144;
  if (idx < 131072){
    int n = idx>>7, k = idx&127; float w = Wx[k*1024+n];
    u16 h = f2bf(w); WxTh[idx] = h; WxTl[idx] = f2bf(w - bf2f(h)); return;
  }
  idx -= 131072;
  if (idx < 16384){
    int n = idx>>7, k = idx&127; float w = Wef1[k*128+n];
    u16 h = f2bf(w); Wef1h[idx] = h; Wef1l[idx] = f2bf(w - bf2f(h)); return;
  }
  idx -= 16384;
  if (idx < 32768){
    int n = idx>>7, k = idx&127; float w = Wef3[k*256+n];
    u16 h = f2bf(w); Wef3h[idx] = h; Wef3l[idx] = f2bf(w - bf2f(h)); return;
  }
}

__global__ void k_zeroflags(unsigned* __restrict__ f){
  f[blockIdx.x*256 + threadIdx.x] = 0u;
}

// ---------------- K1: embedding (chunked): rows m = sc*64 + b, hi/lo outputs ----------------
__global__ __launch_bounds__(256) void k_embed(
    const float* __restrict__ event, const float* __restrict__ vc, const float* __restrict__ vn,
    const float* __restrict__ Ve, const float* __restrict__ Vc, const float* __restrict__ Vn,
    u16* __restrict__ sHi, u16* __restrict__ sLo,
    u16* __restrict__ xHi, u16* __restrict__ xLo, int c0){
  __shared__ float VeL[64*128];
  __shared__ float VcL[32*128];
  __shared__ float VnL[16*128];
  __shared__ float evL[16*64];
  __shared__ float vcL[16*32];
  __shared__ float vnL[16*16];
  const int tid = threadIdx.x;
  const int sc = blockIdx.x >> 2;
  const int b0 = (blockIdx.x & 3) * 16;
  const int ss = c0 + sc;
  for (int i = tid; i < 64*128; i += 256) VeL[i] = Ve[i];
  for (int i = tid; i < 32*128; i += 256) VcL[i] = Vc[i];
  for (int i = tid; i < 16*128; i += 256) VnL[i] = Vn[i];
  for (int i = tid; i < 16*64; i += 256)
    evL[i] = event[((size_t)(b0 + (i>>6))*4096 + ss)*64 + (i&63)];
  for (int i = tid; i < 16*32; i += 256)
    vcL[i] = vc[((size_t)(b0 + (i>>5))*4096 + ss)*32 + (i&31)];
  for (int i = tid; i < 16*16; i += 256)
    vnL[i] = vn[((size_t)(b0 + (i>>4))*4096 + ss)*16 + (i&15)];
  __syncthreads();
  const int n = tid & 127, half = tid >> 7;
  for (int r = half; r < 16; r += 2){
    float sd = 0.f, cd = 0.f, nd = 0.f;
    #pragma unroll 8
    for (int k = 0; k < 64; ++k) sd = fmaf(evL[r*64+k], VeL[k*128+n], sd);
    #pragma unroll 8
    for (int k = 0; k < 32; ++k) cd = fmaf(vcL[r*32+k], VcL[k*128+n], cd);
    #pragma unroll 8
    for (int k = 0; k < 16; ++k) nd = fmaf(vnL[r*16+k], VnL[k*128+n], nd);
    float x = sd + 2.f*(cd + tanh_f(nd));
    size_t o = ((size_t)sc*64 + b0 + r)*128 + n;
    u16 sh = f2bf(sd); sHi[o] = sh; sLo[o] = f2bf(sd - bf2f(sh));
    u16 xh = f2bf(x);  xHi[o] = xh; xLo[o] = f2bf(x  - bf2f(xh));
  }
}

// ---------------- K2: split-bf16 ("bf16x3") MFMA GEMM, K=128, act+bias epilogue ----------------
// OUTKIND 0: f32 C[m][N]   1: f32 xw gate-interleaved [m][hid][gate]   2: hi/lo bf16 planes [m][N]
template<int ACT, int OUTKIND, int NTILES>
__global__ __launch_bounds__(256) void k_gemm(
    const u16* __restrict__ Ahi, const u16* __restrict__ Alo,
    const u16* __restrict__ BTh, const u16* __restrict__ BTl,
    const float* __restrict__ bias,
    float* __restrict__ CoutF, u16* __restrict__ CoutHi, u16* __restrict__ CoutLo){
  __shared__ u16 aLh[4][16*136];
  __shared__ u16 aLl[4][16*136];
  const int tid = threadIdx.x, lane = tid & 63, w = tid >> 6;
  const int c15 = lane & 15, q4 = lane >> 4;
  const size_t mbase = (size_t)blockIdx.x*64 + (size_t)w*16;
  const u16* Aph = Ahi + mbase*128;
  const u16* Apl = Alo + mbase*128;
  #pragma unroll
  for (int i = 0; i < 4; ++i){
    int row = q4 + i*4;
    *(bf16x8*)(&aLh[w][row*136 + c15*8]) = *(const bf16x8*)(Aph + row*128 + c15*8);
    *(bf16x8*)(&aLl[w][row*136 + c15*8]) = *(const bf16x8*)(Apl + row*128 + c15*8);
  }
  __syncthreads();
  bf16x8 ah[4], al[4];
  #pragma unroll
  for (int q = 0; q < 4; ++q){
    ah[q] = *(const bf16x8*)(&aLh[w][c15*136 + q*32 + q4*8]);
    al[q] = *(const bf16x8*)(&aLl[w][c15*136 + q*32 + q4*8]);
  }
  const u16* Bph = BTh + c15*128 + q4*8;
  const u16* Bpl = BTl + c15*128 + q4*8;

  bf16x8 bh[4], bl[4], bhn[4], bln[4];
  #pragma unroll
  for (int q = 0; q < 4; ++q){ bh[q] = *(const bf16x8*)(Bph + q*32); bl[q] = *(const bf16x8*)(Bpl + q*32); }

  for (int nt = 0; nt < NTILES; ++nt){
    if (nt + 1 < NTILES){
      #pragma unroll
      for (int q = 0; q < 4; ++q){
        bhn[q] = *(const bf16x8*)(Bph + (nt+1)*2048 + q*32);
        bln[q] = *(const bf16x8*)(Bpl + (nt+1)*2048 + q*32);
      }
    }
    f32x4 acc = (f32x4){0.f,0.f,0.f,0.f};
    #pragma unroll
    for (int q = 0; q < 4; ++q){
      acc = __builtin_amdgcn_mfma_f32_16x16x32_bf16(al[q], bh[q], acc, 0, 0, 0);
      acc = __builtin_amdgcn_mfma_f32_16x16x32_bf16(ah[q], bl[q], acc, 0, 0, 0);
      acc = __builtin_amdgcn_mfma_f32_16x16x32_bf16(ah[q], bh[q], acc, 0, 0, 0);
    }
    const int n = nt*16 + c15;
    const float bv = bias[n];
    #pragma unroll
    for (int i = 0; i < 4; ++i){
      float v = acc[i] + bv;
      if (ACT == 1) v = tanh_f(v);
      else if (ACT == 2) v = sigmoid_f(v);
      const size_t m = mbase + q4*4 + i;
      if (OUTKIND == 0){
        CoutF[m*(size_t)(NTILES*16) + n] = v;
      } else if (OUTKIND == 1){
        CoutF[m*1024 + (size_t)(n & 255)*4 + (size_t)(n >> 8)] = v;
      } else {
        size_t o = m*(size_t)(NTILES*16) + n;
        u16 hh = f2bf(v); CoutHi[o] = hh; CoutLo[o] = f2bf(v - bf2f(hh));
      }
    }
    #pragma unroll
    for (int q = 0; q < 4; ++q){ bh[q] = bhn[q]; bl[q] = bln[q]; }
  }
}

// ---------------- K3: the scan (chunked) ----------------
// 16 WGs = 4 batch-groups x 4 N-slots (64 hid each). Wh slice register-resident (bf16).
// xw/j consumed as f32. Cross-slot h exchange via agent-scope stores + monotonic flags.
__global__ __launch_bounds__(256, 1) void k_scan(
    const u16* __restrict__ WhT, const float* __restrict__ xwG, const float* __restrict__ jG,
    const float* __restrict__ Wc, const float* __restrict__ h0, const float* __restrict__ c0in,
    const float* __restrict__ Wlin, const float* __restrict__ blin,
    u16* __restrict__ hX, unsigned* __restrict__ flags, float* __restrict__ stateF,
    float* __restrict__ out, int T0, int SC, int FINAL)
{
  __shared__ u16   hA[2][16*272];
  __shared__ float xwL[2][4096];   // [row][hid_local][gate] f32, slice-contiguous
  __shared__ float jL[2][1024];
  __shared__ float hF[16*256];

  const int tid  = threadIdx.x;
  const int lane = tid & 63;
  const int w    = tid >> 6;
  const int g    = blockIdx.x & 3;
  const int s    = blockIdx.x >> 2;
  const int c15  = lane & 15;
  const int q4   = lane >> 4;
  const int hl   = w*16 + c15;
  const int ghid = s*64 + hl;
  const int FIRST = (T0 == 0);

  bf16x8 Bf[4][8];
  {
    const u16* bp = WhT + (size_t)ghid*256 + q4*8;
    #pragma unroll
    for (int gt = 0; gt < 4; ++gt)
      #pragma unroll
      for (int q = 0; q < 8; ++q)
        Bf[gt][q] = *(const bf16x8*)(bp + (size_t)gt*65536 + q*32);
  }

  float creg[4], hreg[4];
  if (FIRST){
    for (int idx = tid; idx < 16*256; idx += 256){
      int r = idx >> 8, k = idx & 255;
      hA[1][r*272 + k] = f2bf(h0[(size_t)(g*16 + r)*256 + k]);
    }
    #pragma unroll
    for (int i = 0; i < 4; ++i){
      int r = q4*4 + i;
      creg[i] = c0in[(size_t)(g*16 + r)*256 + ghid];
      hreg[i] = h0[(size_t)(g*16 + r)*256 + ghid];
    }
  } else {
    #pragma unroll
    for (int i = 0; i < 4; ++i){
      int r = q4*4 + i;
      creg[i] = stateF[(size_t)(g*16 + r)*256 + ghid];
      hreg[i] = stateF[16384 + (size_t)(g*16 + r)*256 + ghid];
    }
  }
  const float wc0 = Wc[ghid], wc1 = Wc[256 + ghid], wc2 = Wc[512 + ghid];

  unsigned* myflag = flags + (g*4 + s)*32;
  unsigned* pf1 = flags + (g*4 + ((s+1)&3))*32;
  unsigned* pf2 = flags + (g*4 + ((s+2)&3))*32;
  unsigned* pf3 = flags + (g*4 + ((s+3)&3))*32;

  auto prefetch = [&](int tn, int pb){
    const float* xws = xwG + ((size_t)tn*64 + g*16)*1024 + s*256;
    #pragma unroll
    for (int cc = 0; cc < 4; ++cc){
      int c = w + cc*4;                 // 0..15
      int chunk = c*64 + lane;          // 0..1023 (16B chunks; row = 64 chunks)
      glds16(xws + (chunk>>6)*1024 + (chunk&63)*4, &xwL[pb][c*256]);
    }
    {
      const float* js = jG + ((size_t)tn*64 + g*16)*256 + s*64;
      int chunk = w*64 + lane;          // 0..255 (row = 16 chunks)
      glds16(js + (chunk>>4)*256 + (chunk&15)*4, &jL[pb][w*256]);
    }
  };

  prefetch(0, 0);
  __syncthreads();

  const int aoff = c15*272 + q4*8;

  for (int t = 0; t < SC; ++t){
    const int par = t & 1;
    if (t + 1 < SC) prefetch(t+1, par^1);

    bf16x8 Af[8];
    if (t == 0 && FIRST){
      #pragma unroll
      for (int q = 0; q < 8; ++q)
        Af[q] = *(const bf16x8*)(&hA[1][aoff + q*32]);
    } else if (t == 0){
      const u64* hx = (const u64*)(hX + (size_t)(1*4 + g)*4096);
      #pragma unroll
      for (int q = 0; q < 8; ++q){
        const u64* p = hx + c15*64 + q*8 + q4*2;
        union { u64 u[2]; bf16x8 v; } cv;
        cv.u[0] = agld64(p); cv.u[1] = agld64(p + 1);
        Af[q] = cv.v;
      }
    } else {
      #pragma unroll
      for (int q = 0; q < 8; ++q)
        if ((q >> 1) == s)
          Af[q] = *(const bf16x8*)(&hA[par^1][aoff + q*32]);
      const unsigned tgt = (unsigned)(T0 + t);
      while (__hip_atomic_load(pf1, __ATOMIC_ACQUIRE, __HIP_MEMORY_SCOPE_AGENT) < tgt) {}
      while (__hip_atomic_load(pf2, __ATOMIC_ACQUIRE, __HIP_MEMORY_SCOPE_AGENT) < tgt) {}
      while (__hip_atomic_load(pf3, __ATOMIC_ACQUIRE, __HIP_MEMORY_SCOPE_AGENT) < tgt) {}
      const u64* hx = (const u64*)(hX + (size_t)((par^1)*4 + g)*4096);
      #pragma unroll
      for (int q = 0; q < 8; ++q){
        if ((q >> 1) != s){
          const u64* p = hx + c15*64 + q*8 + q4*2;
          union { u64 u[2]; bf16x8 v; } cv;
          cv.u[0] = agld64(p); cv.u[1] = agld64(p + 1);
          Af[q] = cv.v;
        }
      }
    }

    f32x4 acc[4];
    #pragma unroll
    for (int gt = 0; gt < 4; ++gt) acc[gt] = (f32x4){0.f,0.f,0.f,0.f};
    #pragma unroll
    for (int q = 0; q < 8; ++q)
      #pragma unroll
      for (int gt = 0; gt < 4; ++gt)
        acc[gt] = __builtin_amdgcn_mfma_f32_16x16x32_bf16(Af[q], Bf[gt][q], acc[gt], 0, 0, 0);

    u16* hxw = hX + (size_t)(par*4 + g)*4096;
    #pragma unroll
    for (int i = 0; i < 4; ++i){
      const int r = q4*4 + i;
      f32x4 xq = *(const f32x4*)(&xwL[par][r*256 + hl*4]);
      float jv = jL[par][r*64 + hl];
      float ip = acc[0][i] + xq[0] + creg[i]*wc0;
      float fp = acc[1][i] + xq[1] + creg[i]*wc1;
      float gp = acc[2][i] + xq[2];
      float op = acc[3][i] + xq[3] + creg[i]*wc2;
      float it = sigmoid_f(ip);
      float ft = sigmoid_f(fp);
      float gt = tanh_f(gp);
      float ot = sigmoid_f(op);
      float chat = ft*creg[i] + it*gt;
      float cn = creg[i] + jv*(chat - creg[i]);
      float hhat = ot*tanh_f(chat);
      float hn = hreg[i] + jv*(hhat - hreg[i]);
      creg[i] = cn; hreg[i] = hn;
      u16 hb = f2bf(hn);
      hA[par][r*272 + ghid] = hb;
      agst16(hxw + r*256 + ghid, hb);
    }

    __syncthreads();
    if (tid == 0)
      __hip_atomic_store(myflag, (unsigned)(T0 + t + 1), __ATOMIC_RELEASE, __HIP_MEMORY_SCOPE_AGENT);
  }

  // persist f32 state for next chunk (and for the epilogue's exact h)
  #pragma unroll
  for (int i = 0; i < 4; ++i){
    int r = q4*4 + i;
    stateF[(size_t)(g*16 + r)*256 + ghid] = creg[i];
    stateF[16384 + (size_t)(g*16 + r)*256 + ghid] = hreg[i];
  }
  __syncthreads();

  if (FINAL){
    if (tid == 0)
      __hip_atomic_store(myflag, (unsigned)(NS + 1), __ATOMIC_RELEASE, __HIP_MEMORY_SCOPE_AGENT);
    if (s == 0){
      const unsigned tgt = (unsigned)(NS + 1);
      while (__hip_atomic_load(pf1, __ATOMIC_ACQUIRE, __HIP_MEMORY_SCOPE_AGENT) < tgt) {}
      while (__hip_atomic_load(pf2, __ATOMIC_ACQUIRE, __HIP_MEMORY_SCOPE_AGENT) < tgt) {}
      while (__hip_atomic_load(pf3, __ATOMIC_ACQUIRE, __HIP_MEMORY_SCOPE_AGENT) < tgt) {}
      for (int idx = tid; idx < 4096; idx += 256){
        int r = idx >> 8, k = idx & 255;
        hF[idx] = agldf(&stateF[16384 + (size_t)(g*16 + r)*256 + k]);
      }
      __syncthreads();
      for (int idx = tid; idx < 1024; idx += 256){
        int r = idx >> 6, d = idx & 63;
        float a = blin[d];
        for (int k = 0; k < 256; ++k)
          a = fmaf(hF[r*256 + k], Wlin[k*64 + d], a);
        out[(size_t)(g*16 + r)*64 + d] = a;
      }
    }
  }
}

// ---------------- host ----------------
extern "C" void kernel_launch(void* const* d_in, const int* in_sizes, int n_in,
                              void* d_out, int out_size, void* d_ws, size_t ws_size,
                              hipStream_t stream)
{
  (void)in_sizes; (void)n_in;
  const float* event = (const float*)d_in[0];
  const float* vc    = (const float*)d_in[2];
  const float* vn    = (const float*)d_in[3];
  const float* h0    = (const float*)d_in[4];
  const float* c0v   = (const float*)d_in[5];
  const float* Wx    = (const float*)d_in[6];
  const float* Wh    = (const float*)d_in[7];
  const float* Wc    = (const float*)d_in[8];
  const float* bias  = (const float*)d_in[9];
  const float* Ve    = (const float*)d_in[10];
  const float* Vc    = (const float*)d_in[11];
  const float* Vn    = (const float*)d_in[12];
  const float* Wlin  = (const float*)d_in[13];
  const float* blin  = (const float*)d_in[14];
  const float* Wef1  = (const float*)d_in[15];
  const float* bef1  = (const float*)d_in[16];
  const float* Wef3  = (const float*)d_in[17];
  const float* bef3  = (const float*)d_in[18];

  int SC = 0;
  const int cands[9] = {4096, 2048, 1024, 512, 256, 128, 64, 32, 16};
  for (int i = 0; i < 9; ++i){
    if (OFF_CH + (size_t)cands[i]*CH_BYTES_PER_SC <= ws_size){ SC = cands[i]; break; }
  }
  if (SC == 0){
    hipMemsetAsync(d_out, 0, (size_t)out_size*sizeof(float), stream);
    return;
  }
  const int C = NS / SC;

  char* ws = (char*)d_ws;
  unsigned* flags = (unsigned*)(ws + OFF_FLAGS);
  u16*   hX     = (u16*)(ws + OFF_HX);
  float* stateF = (float*)(ws + OFF_STATE);
  u16* WhT   = (u16*)(ws + OFF_WHT);
  u16* WxTh  = (u16*)(ws + OFF_WXTH);
  u16* WxTl  = (u16*)(ws + OFF_WXTL);
  u16* Wef1h = (u16*)(ws + OFF_WEF1H);
  u16* Wef1l = (u16*)(ws + OFF_WEF1L);
  u16* Wef3h = (u16*)(ws + OFF_WEF3H);
  u16* Wef3l = (u16*)(ws + OFF_WEF3L);
  char* ch = ws + OFF_CH;
  u16* sHi  = (u16*)ch;
  u16* sLo  = (u16*)(ch + (size_t)SC*16384);
  u16* xHi  = (u16*)(ch + (size_t)SC*32768);
  u16* xLo  = (u16*)(ch + (size_t)SC*49152);
  u16* e1Hi = (u16*)(ch + (size_t)SC*65536);
  u16* e1Lo = (u16*)(ch + (size_t)SC*81920);
  float* xwG = (float*)(ch + (size_t)SC*98304);
  float* jG  = (float*)(ch + (size_t)SC*360448);

  k_prep<<<1728, 256, 0, stream>>>(Wh, Wx, Wef1, Wef3, WhT, WxTh, WxTl,
                                   Wef1h, Wef1l, Wef3h, Wef3l);
  k_zeroflags<<<4, 256, 0, stream>>>(flags);

  for (int c = 0; c < C; ++c){
    const int c0 = c * SC;
    k_embed<<<SC*4, 256, 0, stream>>>(event, vc, vn, Ve, Vc, Vn, sHi, sLo, xHi, xLo, c0);
    k_gemm<0,1,64><<<SC, 256, 0, stream>>>(xHi, xLo, WxTh, WxTl, bias, xwG, nullptr, nullptr);
    k_gemm<1,2,8><<<SC, 256, 0, stream>>>(sHi, sLo, Wef1h, Wef1l, bef1, nullptr, e1Hi, e1Lo);
    k_gemm<2,0,16><<<SC, 256, 0, stream>>>(e1Hi, e1Lo, Wef3h, Wef3l, bef3, jG, nullptr, nullptr);
    k_scan<<<16, 256, 0, stream>>>(WhT, xwG, jG, Wc, h0, c0v, Wlin, blin,
                                   hX, flags, stateF, (float*)d_out, c0, SC, (c == C-1) ? 1 : 0);
  }
}

// Round 5
// 17560.527 us; speedup vs baseline: 1.3546x; 1.3546x over previous
//
#include <hip/hip_runtime.h>
#include <cstdint>
#include <cstddef>

typedef __attribute__((ext_vector_type(8))) short bf16x8;
typedef __attribute__((ext_vector_type(4))) float f32x4;
typedef uint16_t u16;
typedef uint64_t u64;

#define NS 4096

// ---------------- fixed workspace layout (bytes) ----------------
#define OFF_FLAGS  ((size_t)0)                        //   4 KB
#define OFF_HX     ((size_t)4096)                     //  64 KB
#define OFF_STATE  ((size_t)(4096 + 65536))           // 128 KB: c then h, f32 [64][256] each
#define OFF_WHT    ((size_t)204800)                   // 512 KB
#define OFF_WXTH   (OFF_WHT   + (size_t)524288)
#define OFF_WXTL   (OFF_WXTH  + (size_t)262144)
#define OFF_WEF1H  (OFF_WXTL  + (size_t)262144)
#define OFF_WEF1L  (OFF_WEF1H + (size_t)32768)
#define OFF_WEF3H  (OFF_WEF1L + (size_t)32768)
#define OFF_WEF3L  (OFF_WEF3H + (size_t)65536)
#define OFF_CH     ((size_t)2*1024*1024)              // chunk region
// per-step: s hi/lo + x hi/lo + e1 hi/lo (6x16KB) + xw f32 (256KB) + j f32 (64KB)
#define CH_BYTES_PER_SC ((size_t)425984)

// ---------------- helpers ----------------
static __device__ __forceinline__ float bf2f(u16 u){
  union { uint32_t i; float f; } v; v.i = ((uint32_t)u) << 16; return v.f;
}
static __device__ __forceinline__ u16 f2bf(float f){
  union { float f; uint32_t u; } v; v.f = f;
  uint32_t r = v.u + 0x7fffu + ((v.u >> 16) & 1u);
  return (u16)(r >> 16);
}
static __device__ __forceinline__ float sigmoid_f(float x){
  return 1.f / (1.f + __expf(-x));
}
static __device__ __forceinline__ float tanh_f(float x){
  x = fminf(15.f, fmaxf(-15.f, x));
  float e = __expf(2.f * x);
  return 1.f - 2.f / (e + 1.f);
}
static __device__ __forceinline__ void glds16(const void* gp, void* lp){
  typedef __attribute__((address_space(1))) const unsigned int GU;
  typedef __attribute__((address_space(3))) unsigned int LU;
  __builtin_amdgcn_global_load_lds((GU*)gp, (LU*)lp, 16, 0, 0);
}
// All exchange traffic uses RELAXED agent-scope atomics: they bypass L1/L2 to
// the coherence point (MALL), so no acquire/release cache ops are needed.
// Ordering: __syncthreads() drains vmcnt(0) (store acks at MALL) before the
// flag store; consumer waves issue data loads after the poll load returns
// (in-order issue). This removes the per-poll L2-invalidate storm of r4.
static __device__ __forceinline__ u64 agld64(const u64* p){
  return __hip_atomic_load(p, __ATOMIC_RELAXED, __HIP_MEMORY_SCOPE_AGENT);
}
static __device__ __forceinline__ float agldf(const float* p){
  return __hip_atomic_load(p, __ATOMIC_RELAXED, __HIP_MEMORY_SCOPE_AGENT);
}
static __device__ __forceinline__ unsigned agldu(const unsigned* p){
  return __hip_atomic_load(p, __ATOMIC_RELAXED, __HIP_MEMORY_SCOPE_AGENT);
}
static __device__ __forceinline__ void agst16(u16* p, u16 v){
  __hip_atomic_store(p, v, __ATOMIC_RELAXED, __HIP_MEMORY_SCOPE_AGENT);
}
static __device__ __forceinline__ void agstf(float* p, float v){
  __hip_atomic_store(p, v, __ATOMIC_RELAXED, __HIP_MEMORY_SCOPE_AGENT);
}
static __device__ __forceinline__ void agstu(unsigned* p, unsigned v){
  __hip_atomic_store(p, v, __ATOMIC_RELAXED, __HIP_MEMORY_SCOPE_AGENT);
}

// ---------------- K0: weight transpose/convert (hi/lo split for GEMM weights) ----------------
__global__ void k_prep(const float* __restrict__ Wh, const float* __restrict__ Wx,
                       const float* __restrict__ Wef1, const float* __restrict__ Wef3,
                       u16* __restrict__ WhT,
                       u16* __restrict__ WxTh, u16* __restrict__ WxTl,
                       u16* __restrict__ Wef1h, u16* __restrict__ Wef1l,
                       u16* __restrict__ Wef3h, u16* __restrict__ Wef3l){
  int idx = blockIdx.x*256 + threadIdx.x;
  if (idx < 262144){ int n = idx>>8, k = idx&255; WhT[idx] = f2bf(Wh[k*1024+n]); return; }
  idx -= 262144;
  if (idx < 131072){
    int n = idx>>7, k = idx&127; float w = Wx[k*1024+n];
    u16 h = f2bf(w); WxTh[idx] = h; WxTl[idx] = f2bf(w - bf2f(h)); return;
  }
  idx -= 131072;
  if (idx < 16384){
    int n = idx>>7, k = idx&127; float w = Wef1[k*128+n];
    u16 h = f2bf(w); Wef1h[idx] = h; Wef1l[idx] = f2bf(w - bf2f(h)); return;
  }
  idx -= 16384;
  if (idx < 32768){
    int n = idx>>7, k = idx&127; float w = Wef3[k*256+n];
    u16 h = f2bf(w); Wef3h[idx] = h; Wef3l[idx] = f2bf(w - bf2f(h)); return;
  }
}

__global__ void k_zeroflags(unsigned* __restrict__ f){
  f[blockIdx.x*256 + threadIdx.x] = 0u;
}

// ---------------- K1: embedding (chunked): rows m = sc*64 + b, hi/lo outputs ----------------
__global__ __launch_bounds__(256) void k_embed(
    const float* __restrict__ event, const float* __restrict__ vc, const float* __restrict__ vn,
    const float* __restrict__ Ve, const float* __restrict__ Vc, const float* __restrict__ Vn,
    u16* __restrict__ sHi, u16* __restrict__ sLo,
    u16* __restrict__ xHi, u16* __restrict__ xLo, int c0){
  __shared__ float VeL[64*128];
  __shared__ float VcL[32*128];
  __shared__ float VnL[16*128];
  __shared__ float evL[16*64];
  __shared__ float vcL[16*32];
  __shared__ float vnL[16*16];
  const int tid = threadIdx.x;
  const int sc = blockIdx.x >> 2;
  const int b0 = (blockIdx.x & 3) * 16;
  const int ss = c0 + sc;
  for (int i = tid; i < 64*128; i += 256) VeL[i] = Ve[i];
  for (int i = tid; i < 32*128; i += 256) VcL[i] = Vc[i];
  for (int i = tid; i < 16*128; i += 256) VnL[i] = Vn[i];
  for (int i = tid; i < 16*64; i += 256)
    evL[i] = event[((size_t)(b0 + (i>>6))*4096 + ss)*64 + (i&63)];
  for (int i = tid; i < 16*32; i += 256)
    vcL[i] = vc[((size_t)(b0 + (i>>5))*4096 + ss)*32 + (i&31)];
  for (int i = tid; i < 16*16; i += 256)
    vnL[i] = vn[((size_t)(b0 + (i>>4))*4096 + ss)*16 + (i&15)];
  __syncthreads();
  const int n = tid & 127, half = tid >> 7;
  for (int r = half; r < 16; r += 2){
    float sd = 0.f, cd = 0.f, nd = 0.f;
    #pragma unroll 8
    for (int k = 0; k < 64; ++k) sd = fmaf(evL[r*64+k], VeL[k*128+n], sd);
    #pragma unroll 8
    for (int k = 0; k < 32; ++k) cd = fmaf(vcL[r*32+k], VcL[k*128+n], cd);
    #pragma unroll 8
    for (int k = 0; k < 16; ++k) nd = fmaf(vnL[r*16+k], VnL[k*128+n], nd);
    float x = sd + 2.f*(cd + tanh_f(nd));
    size_t o = ((size_t)sc*64 + b0 + r)*128 + n;
    u16 sh = f2bf(sd); sHi[o] = sh; sLo[o] = f2bf(sd - bf2f(sh));
    u16 xh = f2bf(x);  xHi[o] = xh; xLo[o] = f2bf(x  - bf2f(xh));
  }
}

// ---------------- K2: split-bf16 ("bf16x3") MFMA GEMM, K=128, act+bias epilogue ----------------
// OUTKIND 0: f32 C[m][N]   1: f32 xw gate-interleaved [m][hid][gate]   2: hi/lo bf16 planes [m][N]
template<int ACT, int OUTKIND, int NTILES>
__global__ __launch_bounds__(256) void k_gemm(
    const u16* __restrict__ Ahi, const u16* __restrict__ Alo,
    const u16* __restrict__ BTh, const u16* __restrict__ BTl,
    const float* __restrict__ bias,
    float* __restrict__ CoutF, u16* __restrict__ CoutHi, u16* __restrict__ CoutLo){
  __shared__ u16 aLh[4][16*136];
  __shared__ u16 aLl[4][16*136];
  const int tid = threadIdx.x, lane = tid & 63, w = tid >> 6;
  const int c15 = lane & 15, q4 = lane >> 4;
  const size_t mbase = (size_t)blockIdx.x*64 + (size_t)w*16;
  const u16* Aph = Ahi + mbase*128;
  const u16* Apl = Alo + mbase*128;
  #pragma unroll
  for (int i = 0; i < 4; ++i){
    int row = q4 + i*4;
    *(bf16x8*)(&aLh[w][row*136 + c15*8]) = *(const bf16x8*)(Aph + row*128 + c15*8);
    *(bf16x8*)(&aLl[w][row*136 + c15*8]) = *(const bf16x8*)(Apl + row*128 + c15*8);
  }
  __syncthreads();
  bf16x8 ah[4], al[4];
  #pragma unroll
  for (int q = 0; q < 4; ++q){
    ah[q] = *(const bf16x8*)(&aLh[w][c15*136 + q*32 + q4*8]);
    al[q] = *(const bf16x8*)(&aLl[w][c15*136 + q*32 + q4*8]);
  }
  const u16* Bph = BTh + c15*128 + q4*8;
  const u16* Bpl = BTl + c15*128 + q4*8;

  bf16x8 bh[4], bl[4], bhn[4], bln[4];
  #pragma unroll
  for (int q = 0; q < 4; ++q){ bh[q] = *(const bf16x8*)(Bph + q*32); bl[q] = *(const bf16x8*)(Bpl + q*32); }

  for (int nt = 0; nt < NTILES; ++nt){
    if (nt + 1 < NTILES){
      #pragma unroll
      for (int q = 0; q < 4; ++q){
        bhn[q] = *(const bf16x8*)(Bph + (nt+1)*2048 + q*32);
        bln[q] = *(const bf16x8*)(Bpl + (nt+1)*2048 + q*32);
      }
    }
    f32x4 acc = (f32x4){0.f,0.f,0.f,0.f};
    #pragma unroll
    for (int q = 0; q < 4; ++q){
      acc = __builtin_amdgcn_mfma_f32_16x16x32_bf16(al[q], bh[q], acc, 0, 0, 0);
      acc = __builtin_amdgcn_mfma_f32_16x16x32_bf16(ah[q], bl[q], acc, 0, 0, 0);
      acc = __builtin_amdgcn_mfma_f32_16x16x32_bf16(ah[q], bh[q], acc, 0, 0, 0);
    }
    const int n = nt*16 + c15;
    const float bv = bias[n];
    #pragma unroll
    for (int i = 0; i < 4; ++i){
      float v = acc[i] + bv;
      if (ACT == 1) v = tanh_f(v);
      else if (ACT == 2) v = sigmoid_f(v);
      const size_t m = mbase + q4*4 + i;
      if (OUTKIND == 0){
        CoutF[m*(size_t)(NTILES*16) + n] = v;
      } else if (OUTKIND == 1){
        CoutF[m*1024 + (size_t)(n & 255)*4 + (size_t)(n >> 8)] = v;
      } else {
        size_t o = m*(size_t)(NTILES*16) + n;
        u16 hh = f2bf(v); CoutHi[o] = hh; CoutLo[o] = f2bf(v - bf2f(hh));
      }
    }
    #pragma unroll
    for (int q = 0; q < 4; ++q){ bh[q] = bhn[q]; bl[q] = bln[q]; }
  }
}

// ---------------- K3: the scan (chunked) ----------------
// 16 WGs = 4 batch-groups x 4 N-slots. Wh slice register-resident (bf16).
// Exchange: relaxed agent atomics only; barrier drain provides data-before-flag.
__global__ __launch_bounds__(256, 1) void k_scan(
    const u16* __restrict__ WhT, const float* __restrict__ xwG, const float* __restrict__ jG,
    const float* __restrict__ Wc, const float* __restrict__ h0, const float* __restrict__ c0in,
    const float* __restrict__ Wlin, const float* __restrict__ blin,
    u16* __restrict__ hX, unsigned* __restrict__ flags, float* __restrict__ stateF,
    float* __restrict__ out, int T0, int SC, int FINAL)
{
  __shared__ u16   hA[2][16*272];
  __shared__ float xwL[2][4096];   // [row][hid_local][gate] f32, slice-contiguous
  __shared__ float jL[2][1024];
  __shared__ float hF[16*256];

  const int tid  = threadIdx.x;
  const int lane = tid & 63;
  const int w    = tid >> 6;
  const int g    = blockIdx.x & 3;
  const int s    = blockIdx.x >> 2;
  const int c15  = lane & 15;
  const int q4   = lane >> 4;
  const int hl   = w*16 + c15;
  const int ghid = s*64 + hl;
  const int FIRST = (T0 == 0);

  bf16x8 Bf[4][8];
  {
    const u16* bp = WhT + (size_t)ghid*256 + q4*8;
    #pragma unroll
    for (int gt = 0; gt < 4; ++gt)
      #pragma unroll
      for (int q = 0; q < 8; ++q)
        Bf[gt][q] = *(const bf16x8*)(bp + (size_t)gt*65536 + q*32);
  }

  float creg[4], hreg[4];
  if (FIRST){
    for (int idx = tid; idx < 16*256; idx += 256){
      int r = idx >> 8, k = idx & 255;
      hA[1][r*272 + k] = f2bf(h0[(size_t)(g*16 + r)*256 + k]);
    }
    #pragma unroll
    for (int i = 0; i < 4; ++i){
      int r = q4*4 + i;
      creg[i] = c0in[(size_t)(g*16 + r)*256 + ghid];
      hreg[i] = h0[(size_t)(g*16 + r)*256 + ghid];
    }
  } else {
    #pragma unroll
    for (int i = 0; i < 4; ++i){
      int r = q4*4 + i;
      creg[i] = stateF[(size_t)(g*16 + r)*256 + ghid];
      hreg[i] = stateF[16384 + (size_t)(g*16 + r)*256 + ghid];
    }
  }
  const float wc0 = Wc[ghid], wc1 = Wc[256 + ghid], wc2 = Wc[512 + ghid];

  unsigned* myflag = flags + (g*4 + s)*32;
  unsigned* pf1 = flags + (g*4 + ((s+1)&3))*32;
  unsigned* pf2 = flags + (g*4 + ((s+2)&3))*32;
  unsigned* pf3 = flags + (g*4 + ((s+3)&3))*32;

  auto prefetch = [&](int tn, int pb){
    const float* xws = xwG + ((size_t)tn*64 + g*16)*1024 + s*256;
    #pragma unroll
    for (int cc = 0; cc < 4; ++cc){
      int c = w + cc*4;                 // 0..15
      int chunk = c*64 + lane;          // 0..1023 (16B chunks; row = 64 chunks)
      glds16(xws + (chunk>>6)*1024 + (chunk&63)*4, &xwL[pb][c*256]);
    }
    {
      const float* js = jG + ((size_t)tn*64 + g*16)*256 + s*64;
      int chunk = w*64 + lane;          // 0..255 (row = 16 chunks)
      glds16(js + (chunk>>4)*256 + (chunk&15)*4, &jL[pb][w*256]);
    }
  };

  prefetch(0, 0);
  __syncthreads();

  const int aoff = c15*272 + q4*8;

  for (int t = 0; t < SC; ++t){
    const int par = t & 1;

    // ---- A fragments FIRST (critical path), prefetch issued after ----
    bf16x8 Af[8];
    if (t == 0 && FIRST){
      #pragma unroll
      for (int q = 0; q < 8; ++q)
        Af[q] = *(const bf16x8*)(&hA[1][aoff + q*32]);
    } else if (t == 0){
      const u64* hx = (const u64*)(hX + (size_t)(1*4 + g)*4096);
      #pragma unroll
      for (int q = 0; q < 8; ++q){
        const u64* p = hx + c15*64 + q*8 + q4*2;
        union { u64 u[2]; bf16x8 v; } cv;
        cv.u[0] = agld64(p); cv.u[1] = agld64(p + 1);
        Af[q] = cv.v;
      }
    } else {
      const unsigned tgt = (unsigned)(T0 + t);
      unsigned fa, fb, fc;
      do {                                   // relaxed polls: pipelined, no cache ops
        fa = agldu(pf1); fb = agldu(pf2); fc = agldu(pf3);
      } while (fa < tgt || fb < tgt || fc < tgt);
      const u64* hx = (const u64*)(hX + (size_t)((par^1)*4 + g)*4096);
      #pragma unroll
      for (int q = 0; q < 8; ++q){           // partner loads issue first (vmcnt order)
        if ((q >> 1) != s){
          const u64* p = hx + c15*64 + q*8 + q4*2;
          union { u64 u[2]; bf16x8 v; } cv;
          cv.u[0] = agld64(p); cv.u[1] = agld64(p + 1);
          Af[q] = cv.v;
        }
      }
      #pragma unroll
      for (int q = 0; q < 8; ++q)
        if ((q >> 1) == s)
          Af[q] = *(const bf16x8*)(&hA[par^1][aoff + q*32]);
    }

    // prefetch AFTER critical-path loads: in-order vmcnt means waiting for the
    // partner h data no longer waits for this 20KB stream.
    if (t + 1 < SC) prefetch(t+1, par^1);

    f32x4 acc[4];
    #pragma unroll
    for (int gt = 0; gt < 4; ++gt) acc[gt] = (f32x4){0.f,0.f,0.f,0.f};
    #pragma unroll
    for (int q = 0; q < 8; ++q)
      #pragma unroll
      for (int gt = 0; gt < 4; ++gt)
        acc[gt] = __builtin_amdgcn_mfma_f32_16x16x32_bf16(Af[q], Bf[gt][q], acc[gt], 0, 0, 0);

    u16* hxw = hX + (size_t)(par*4 + g)*4096;
    #pragma unroll
    for (int i = 0; i < 4; ++i){
      const int r = q4*4 + i;
      f32x4 xq = *(const f32x4*)(&xwL[par][r*256 + hl*4]);
      float jv = jL[par][r*64 + hl];
      float ip = acc[0][i] + xq[0] + creg[i]*wc0;
      float fp = acc[1][i] + xq[1] + creg[i]*wc1;
      float gp = acc[2][i] + xq[2];
      float op = acc[3][i] + xq[3] + creg[i]*wc2;
      float it = sigmoid_f(ip);
      float ft = sigmoid_f(fp);
      float gt = tanh_f(gp);
      float ot = sigmoid_f(op);
      float chat = ft*creg[i] + it*gt;
      float cn = creg[i] + jv*(chat - creg[i]);
      float hhat = ot*tanh_f(chat);
      float hn = hreg[i] + jv*(hhat - hreg[i]);
      creg[i] = cn; hreg[i] = hn;
      u16 hb = f2bf(hn);
      hA[par][r*272 + ghid] = hb;
      agst16(hxw + r*256 + ghid, hb);
    }

    // barrier drains vmcnt(0): all agent stores are at the coherence point
    // before any wave proceeds -> relaxed flag store suffices (data-before-flag).
    __syncthreads();
    if (tid == 0) agstu(myflag, (unsigned)(T0 + t + 1));
  }

  // persist f32 state; h half must be agent-visible within this dispatch (epilogue)
  #pragma unroll
  for (int i = 0; i < 4; ++i){
    int r = q4*4 + i;
    agstf(&stateF[(size_t)(g*16 + r)*256 + ghid], creg[i]);
    agstf(&stateF[16384 + (size_t)(g*16 + r)*256 + ghid], hreg[i]);
  }
  __syncthreads();   // drain persist stores before publishing NS+1

  if (FINAL){
    if (tid == 0) agstu(myflag, (unsigned)(NS + 1));
    if (s == 0){
      const unsigned tgt = (unsigned)(NS + 1);
      unsigned fa, fb, fc;
      do {
        fa = agldu(pf1); fb = agldu(pf2); fc = agldu(pf3);
      } while (fa < tgt || fb < tgt || fc < tgt);
      for (int idx = tid; idx < 4096; idx += 256){
        int r = idx >> 8, k = idx & 255;
        hF[idx] = agldf(&stateF[16384 + (size_t)(g*16 + r)*256 + k]);
      }
      __syncthreads();
      for (int idx = tid; idx < 1024; idx += 256){
        int r = idx >> 6, d = idx & 63;
        float a = blin[d];
        for (int k = 0; k < 256; ++k)
          a = fmaf(hF[r*256 + k], Wlin[k*64 + d], a);
        out[(size_t)(g*16 + r)*64 + d] = a;
      }
    }
  }
}

// ---------------- host ----------------
extern "C" void kernel_launch(void* const* d_in, const int* in_sizes, int n_in,
                              void* d_out, int out_size, void* d_ws, size_t ws_size,
                              hipStream_t stream)
{
  (void)in_sizes; (void)n_in;
  const float* event = (const float*)d_in[0];
  const float* vc    = (const float*)d_in[2];
  const float* vn    = (const float*)d_in[3];
  const float* h0    = (const float*)d_in[4];
  const float* c0v   = (const float*)d_in[5];
  const float* Wx    = (const float*)d_in[6];
  const float* Wh    = (const float*)d_in[7];
  const float* Wc    = (const float*)d_in[8];
  const float* bias  = (const float*)d_in[9];
  const float* Ve    = (const float*)d_in[10];
  const float* Vc    = (const float*)d_in[11];
  const float* Vn    = (const float*)d_in[12];
  const float* Wlin  = (const float*)d_in[13];
  const float* blin  = (const float*)d_in[14];
  const float* Wef1  = (const float*)d_in[15];
  const float* bef1  = (const float*)d_in[16];
  const float* Wef3  = (const float*)d_in[17];
  const float* bef3  = (const float*)d_in[18];

  int SC = 0;
  const int cands[9] = {4096, 2048, 1024, 512, 256, 128, 64, 32, 16};
  for (int i = 0; i < 9; ++i){
    if (OFF_CH + (size_t)cands[i]*CH_BYTES_PER_SC <= ws_size){ SC = cands[i]; break; }
  }
  if (SC == 0){
    hipMemsetAsync(d_out, 0, (size_t)out_size*sizeof(float), stream);
    return;
  }
  const int C = NS / SC;

  char* ws = (char*)d_ws;
  unsigned* flags = (unsigned*)(ws + OFF_FLAGS);
  u16*   hX     = (u16*)(ws + OFF_HX);
  float* stateF = (float*)(ws + OFF_STATE);
  u16* WhT   = (u16*)(ws + OFF_WHT);
  u16* WxTh  = (u16*)(ws + OFF_WXTH);
  u16* WxTl  = (u16*)(ws + OFF_WXTL);
  u16* Wef1h = (u16*)(ws + OFF_WEF1H);
  u16* Wef1l = (u16*)(ws + OFF_WEF1L);
  u16* Wef3h = (u16*)(ws + OFF_WEF3H);
  u16* Wef3l = (u16*)(ws + OFF_WEF3L);
  char* ch = ws + OFF_CH;
  u16* sHi  = (u16*)ch;
  u16* sLo  = (u16*)(ch + (size_t)SC*16384);
  u16* xHi  = (u16*)(ch + (size_t)SC*32768);
  u16* xLo  = (u16*)(ch + (size_t)SC*49152);
  u16* e1Hi = (u16*)(ch + (size_t)SC*65536);
  u16* e1Lo = (u16*)(ch + (size_t)SC*81920);
  float* xwG = (float*)(ch + (size_t)SC*98304);
  float* jG  = (float*)(ch + (size_t)SC*360448);

  k_prep<<<1728, 256, 0, stream>>>(Wh, Wx, Wef1, Wef3, WhT, WxTh, WxTl,
                                   Wef1h, Wef1l, Wef3h, Wef3l);
  k_zeroflags<<<4, 256, 0, stream>>>(flags);

  for (int c = 0; c < C; ++c){
    const int c0 = c * SC;
    k_embed<<<SC*4, 256, 0, stream>>>(event, vc, vn, Ve, Vc, Vn, sHi, sLo, xHi, xLo, c0);
    k_gemm<0,1,64><<<SC, 256, 0, stream>>>(xHi, xLo, WxTh, WxTl, bias, xwG, nullptr, nullptr);
    k_gemm<1,2,8><<<SC, 256, 0, stream>>>(sHi, sLo, Wef1h, Wef1l, bef1, nullptr, e1Hi, e1Lo);
    k_gemm<2,0,16><<<SC, 256, 0, stream>>>(e1Hi, e1Lo, Wef3h, Wef3l, bef3, jG, nullptr, nullptr);
    k_scan<<<16, 256, 0, stream>>>(WhT, xwG, jG, Wc, h0, c0v, Wlin, blin,
                                   hX, flags, stateF, (float*)d_out, c0, SC, (c == C-1) ? 1 : 0);
  }
}